// Round 1
// baseline (30.108 us; speedup 1.0000x reference)
//
#include <hip/hip_runtime.h>

typedef __attribute__((ext_vector_type(4))) float f32x4;
typedef __attribute__((ext_vector_type(8))) short bf16x8;

// Problem constants: x is [B, 64, 128] fp32; out is [B, 2016] fp32.
constexpr int F = 64;
constexpr int D = 128;
constexpr int NPAIR = 2016;   // 64*63/2

// fp32 -> bf16, round-to-nearest-even (inputs are normal floats; NaN not expected)
__device__ inline unsigned short f2bf(float f) {
  unsigned int u = __float_as_uint(f);
  return (unsigned short)((u + 0x7FFFu + ((u >> 16) & 1u)) >> 16);
}

// One block per batch: 256 threads = 4 waves.
// Wave w computes tile-row ti=w of the 4x4 grid of 16x16 gram tiles.
__global__ __launch_bounds__(256)
void gram_upper_kernel(const float* __restrict__ x, float* __restrict__ out) {
  // LDS: 64 rows x 128 bf16 = 64 x 256 B, stored with 16B-granule swizzle
  // granule' = granule ^ (row & 15)  -> conflict-free ds_write_b64 staging
  // and conflict-free ds_read_b128 fragment loads.
  __shared__ __align__(16) unsigned char lds[F * 256];

  const int b = blockIdx.x;
  const int t = threadIdx.x;
  const float* xb = x + (size_t)b * (F * D);

  // ---- Stage: global fp32 (coalesced float4) -> bf16 -> swizzled LDS ----
#pragma unroll
  for (int k = 0; k < 8; ++k) {
    int idx4 = t + 256 * k;                         // float4 index, [0, 2048)
    f32x4 v = reinterpret_cast<const f32x4*>(xb)[idx4];
    int e  = idx4 << 2;                             // element index
    int f  = e >> 7;                                // row 0..63
    int d0 = e & 127;                               // col (multiple of 4)
    int g  = d0 >> 3;                               // 16B granule 0..15
    int gs = g ^ (f & 15);                          // swizzled granule
    unsigned int lo = (unsigned)f2bf(v.x) | ((unsigned)f2bf(v.y) << 16);
    unsigned int hi = (unsigned)f2bf(v.z) | ((unsigned)f2bf(v.w) << 16);
    uint2 pk; pk.x = lo; pk.y = hi;
    *reinterpret_cast<uint2*>(lds + f * 256 + gs * 16 + ((d0 & 7) ? 8 : 0)) = pk;
  }
  __syncthreads();

  // ---- MFMA: 16x16x32 bf16, wave w owns tile-row w ----
  const int w  = t >> 6;     // wave id = ti
  const int l  = t & 63;
  const int lr = l & 15;     // row-within-tile (A) / col-within-tile (B,D)
  const int lk = l >> 4;     // k-group 0..3

  f32x4 acc[4] = {f32x4{0,0,0,0}, f32x4{0,0,0,0}, f32x4{0,0,0,0}, f32x4{0,0,0,0}};

  const int rowA = w * 16 + lr;
#pragma unroll
  for (int kk = 0; kk < 4; ++kk) {
    int gl  = (kk << 2) + lk;     // logical granule = (kk*32 + lk*8) bf16 / 8
    int gsw = gl ^ lr;            // rows below differ by multiples of 16 -> same (row&15)=lr
    bf16x8 a = *reinterpret_cast<const bf16x8*>(lds + rowA * 256 + gsw * 16);
#pragma unroll
    for (int tj = 0; tj < 4; ++tj) {
      bf16x8 bb = *reinterpret_cast<const bf16x8*>(lds + (tj * 16 + lr) * 256 + gsw * 16);
      acc[tj] = __builtin_amdgcn_mfma_f32_16x16x32_bf16(a, bb, acc[tj], 0, 0, 0);
    }
  }

  // ---- Epilogue: write strictly-upper entries ----
  // C/D map (m89-verified): col = lane&15, row = (lane>>4)*4 + reg
  float* ob = out + (size_t)b * NPAIR;
  const int ibase = w * 16 + lk * 4;
#pragma unroll
  for (int tj = 0; tj < 4; ++tj) {
    int j = tj * 16 + lr;
#pragma unroll
    for (int r = 0; r < 4; ++r) {
      int i = ibase + r;
      if (j > i) {
        int p = i * 63 - ((i * (i - 1)) >> 1) + (j - i - 1);
        ob[p] = acc[tj][r];
      }
    }
  }
}

extern "C" void kernel_launch(void* const* d_in, const int* in_sizes, int n_in,
                              void* d_out, int out_size, void* d_ws, size_t ws_size,
                              hipStream_t stream) {
  const float* x = (const float*)d_in[0];
  float* out = (float*)d_out;
  const int B = in_sizes[0] / (F * D);   // 4096
  gram_upper_kernel<<<dim3(B), dim3(256), 0, stream>>>(x, out);
}